// Round 1
// baseline (15562.634 us; speedup 1.0000x reference)
//
#include <hip/hip_runtime.h>
#include <hip/hip_bf16.h>

#define HH 128
#define WW 128

// ---------------------------------------------------------------------------
// Head conv: 3 -> 64, fused mean subtraction. One thread per pixel, loops oc.
// ---------------------------------------------------------------------------
__global__ __launch_bounds__(256)
void head_k(const float* __restrict__ x, const float* __restrict__ w,
            const float* __restrict__ b, float* __restrict__ out) {
    int n  = blockIdx.z;
    int gx = blockIdx.x * 16 + (threadIdx.x & 15);
    int gy = blockIdx.y * 16 + (threadIdx.x >> 4);
    const float msub0 = 255.0f * 0.4488f;
    const float msub1 = 255.0f * 0.4371f;
    const float msub2 = 255.0f * 0.4040f;
    float msub[3] = {msub0, msub1, msub2};
    float iv[27];
#pragma unroll
    for (int c = 0; c < 3; ++c)
#pragma unroll
        for (int dy = 0; dy < 3; ++dy)
#pragma unroll
            for (int dx = 0; dx < 3; ++dx) {
                int yy = gy + dy - 1, xx = gx + dx - 1;
                float v = 0.f;
                if ((unsigned)yy < HH && (unsigned)xx < WW)
                    v = x[(((size_t)n * 3 + c) * HH + yy) * WW + xx] - msub[c];
                iv[c * 9 + dy * 3 + dx] = v;
            }
    for (int oc = 0; oc < 64; ++oc) {
        float a = b[oc];
#pragma unroll
        for (int t = 0; t < 27; ++t) a = fmaf(iv[t], w[oc * 27 + t], a);
        out[(((size_t)n * 64 + oc) * HH + gy) * WW + gx] = a;
    }
}

// ---------------------------------------------------------------------------
// Main 3x3 conv, IC=64, OC multiple of 16. Tile: 32x16 spatial x 16 oc.
// 256 threads; thread = 8-px x-strip x 4 oc. LDS-staged inputs (8-ic chunks,
// stride 35 to break bank conflicts) + weights (wave-uniform broadcast reads).
// Optional fused relu / residual-add / bf16 output.
// ---------------------------------------------------------------------------
template<bool RELU, bool RES, bool OUT_BF16>
__global__ __launch_bounds__(256)
void conv64_k(const float* __restrict__ in, const float* __restrict__ wgt,
              const float* __restrict__ bias, const float* __restrict__ resid,
              void* __restrict__ outp, int OC) {
    constexpr int IC  = 64;
    constexpr int ICC = 8;
    __shared__ float sIn[ICC * 18 * 35];
    __shared__ float sW[ICC * 16 * 9];

    int tid      = threadIdx.x;
    int tilesPerN = OC >> 4;
    int n      = blockIdx.z / tilesPerN;
    int ocBase = (blockIdx.z % tilesPerN) << 4;
    int bx = blockIdx.x, by = blockIdx.y;
    int og = tid >> 6;            // wave-uniform (tid 0..63 -> og 0)
    int ty = (tid >> 2) & 15;
    int x0 = (tid & 3) << 3;

    float acc[4][8];
#pragma unroll
    for (int j = 0; j < 4; ++j)
#pragma unroll
        for (int k = 0; k < 8; ++k) acc[j][k] = 0.f;

    for (int icb = 0; icb < IC; icb += ICC) {
        __syncthreads();
        // stage input chunk (with zero halo)
        for (int i = tid; i < ICC * 18 * 34; i += 256) {
            int c   = i / (18 * 34);
            int rem = i - c * (18 * 34);
            int r   = rem / 34;
            int xc  = rem - r * 34;
            int gy  = by * 16 + r - 1;
            int gx  = bx * 32 + xc - 1;
            float v = 0.f;
            if ((unsigned)gy < HH && (unsigned)gx < WW)
                v = in[(((size_t)n * IC + icb + c) * HH + gy) * WW + gx];
            sIn[(c * 18 + r) * 35 + xc] = v;
        }
        // stage weights: sW[ic][oc][tap]
        for (int i = tid; i < ICC * 16 * 9; i += 256) {
            int tap = i % 9;
            int oc  = (i / 9) & 15;
            int ic  = i / 144;
            sW[i] = wgt[((size_t)(ocBase + oc) * IC + icb + ic) * 9 + tap];
        }
        __syncthreads();
#pragma unroll
        for (int ic = 0; ic < ICC; ++ic) {
            float iv[3][10];
#pragma unroll
            for (int dy = 0; dy < 3; ++dy)
#pragma unroll
                for (int j = 0; j < 10; ++j)
                    iv[dy][j] = sIn[(ic * 18 + ty + dy) * 35 + x0 + j];
#pragma unroll
            for (int j = 0; j < 4; ++j) {
                int oc = (og << 2) + j;
                float w[9];
#pragma unroll
                for (int t = 0; t < 9; ++t) w[t] = sW[(ic * 16 + oc) * 9 + t];
#pragma unroll
                for (int k = 0; k < 8; ++k) {
                    float s = acc[j][k];
#pragma unroll
                    for (int dy = 0; dy < 3; ++dy)
#pragma unroll
                        for (int dx = 0; dx < 3; ++dx)
                            s = fmaf(iv[dy][k + dx], w[dy * 3 + dx], s);
                    acc[j][k] = s;
                }
            }
        }
    }

    int gy  = by * 16 + ty;
    int gx0 = bx * 32 + x0;
#pragma unroll
    for (int j = 0; j < 4; ++j) {
        int oc   = ocBase + (og << 2) + j;
        float bv = bias[oc];
        size_t oi = (((size_t)n * OC + oc) * HH + gy) * WW + gx0;
        float v[8];
#pragma unroll
        for (int k = 0; k < 8; ++k) {
            float t = acc[j][k] + bv;
            if (RELU) t = fmaxf(t, 0.f);
            v[k] = t;
        }
        if (RES) {
            const float4* rp = (const float4*)(resid + oi);
            float4 r0 = rp[0], r1 = rp[1];
            v[0] += r0.x; v[1] += r0.y; v[2] += r0.z; v[3] += r0.w;
            v[4] += r1.x; v[5] += r1.y; v[6] += r1.z; v[7] += r1.w;
        }
        if (OUT_BF16) {
            union { uint4 u; __hip_bfloat16 h[8]; } pk;
#pragma unroll
            for (int k = 0; k < 8; ++k) pk.h[k] = __float2bfloat16(v[k]);
            *((uint4*)((__hip_bfloat16*)outp + oi)) = pk.u;
        } else {
            float* op = (float*)outp + oi;
            ((float4*)op)[0] = make_float4(v[0], v[1], v[2], v[3]);
            ((float4*)op)[1] = make_float4(v[4], v[5], v[6], v[7]);
        }
    }
}

// ---------------------------------------------------------------------------
// Out conv: 100 -> 3 at 256x256, input gathered through pixel-shuffle mapping
// from the 400-channel super output (bf16). Fused mean add.
// t[n,c,y,x] = S[n, c*4 + (y&1)*2 + (x&1), y>>1, x>>1]
// ---------------------------------------------------------------------------
__global__ __launch_bounds__(256)
void out_k(const __hip_bfloat16* __restrict__ S, const float* __restrict__ w,
           const float* __restrict__ b, float* __restrict__ out) {
    int n = blockIdx.z;
    int x = blockIdx.x * 16 + (threadIdx.x & 15);
    int y = blockIdx.y * 16 + (threadIdx.x >> 4);
    float acc0 = 0.f, acc1 = 0.f, acc2 = 0.f;
    for (int ic = 0; ic < 100; ++ic) {
#pragma unroll
        for (int dy = 0; dy < 3; ++dy) {
            int yy = y + dy - 1;
            if ((unsigned)yy >= 256u) continue;
#pragma unroll
            for (int dx = 0; dx < 3; ++dx) {
                int xx = x + dx - 1;
                if ((unsigned)xx >= 256u) continue;
                int ch = ic * 4 + (yy & 1) * 2 + (xx & 1);
                float v = __bfloat162float(
                    S[(((size_t)n * 400 + ch) * 128 + (yy >> 1)) * 128 + (xx >> 1)]);
                int t = dy * 3 + dx;
                acc0 = fmaf(v, w[(0 * 100 + ic) * 9 + t], acc0);
                acc1 = fmaf(v, w[(1 * 100 + ic) * 9 + t], acc1);
                acc2 = fmaf(v, w[(2 * 100 + ic) * 9 + t], acc2);
            }
        }
    }
    const float m0 = 255.0f * 0.4488f, m1 = 255.0f * 0.4371f, m2 = 255.0f * 0.4040f;
    size_t base = ((size_t)n * 3) * 256 * 256 + (size_t)y * 256 + x;
    out[base]                 = acc0 + b[0] + m0;
    out[base + 256 * 256]     = acc1 + b[1] + m1;
    out[base + 2 * 256 * 256] = acc2 + b[2] + m2;
}

// ---------------------------------------------------------------------------
extern "C" void kernel_launch(void* const* d_in, const int* in_sizes, int n_in,
                              void* d_out, int out_size, void* d_ws, size_t ws_size,
                              hipStream_t stream) {
    const float* x       = (const float*)d_in[0];
    const float* head_w  = (const float*)d_in[1];
    const float* head_b  = (const float*)d_in[2];
    const float* rb_w1   = (const float*)d_in[3];
    const float* rb_b1   = (const float*)d_in[4];
    const float* rb_w2   = (const float*)d_in[5];
    const float* rb_b2   = (const float*)d_in[6];
    const float* body_w  = (const float*)d_in[7];
    const float* body_b  = (const float*)d_in[8];
    const float* super_w = (const float*)d_in[9];
    const float* super_b = (const float*)d_in[10];
    const float* out_w   = (const float*)d_in[11];
    const float* out_b   = (const float*)d_in[12];
    float* out = (float*)d_out;

    const size_t actElems = (size_t)8 * 64 * HH * WW;  // 8.39M floats
    float* Hb = (float*)d_ws;
    float* Cb = Hb + actElems;
    float* Tb = Cb + actElems;
    __hip_bfloat16* Sb = (__hip_bfloat16*)(Tb + actElems);  // 8*400*128*128 bf16

    // head: x - mean -> conv 3->64
    head_k<<<dim3(8, 8, 8), 256, 0, stream>>>(x, head_w, head_b, Hb);

    dim3 cgrid(4, 8, 8 * 4);  // 128/32 x-tiles, 128/16 y-tiles, 8n * 4 oc-tiles
    for (int i = 0; i < 16; ++i) {
        const float* cin = (i == 0) ? Hb : Cb;
        conv64_k<true, false, false><<<cgrid, 256, 0, stream>>>(
            cin, rb_w1 + (size_t)i * 64 * 64 * 9, rb_b1 + i * 64, nullptr, Tb, 64);
        conv64_k<false, true, false><<<cgrid, 256, 0, stream>>>(
            Tb, rb_w2 + (size_t)i * 64 * 64 * 9, rb_b2 + i * 64, cin, Cb, 64);
    }
    // body conv + skip from head
    conv64_k<false, true, false><<<cgrid, 256, 0, stream>>>(
        Cb, body_w, body_b, Hb, Tb, 64);
    // super conv 64->400, bf16 out
    conv64_k<false, false, true><<<dim3(4, 8, 8 * 25), 256, 0, stream>>>(
        Tb, super_w, super_b, nullptr, (void*)Sb, 400);
    // out conv over pixel-shuffled view + mean add
    out_k<<<dim3(16, 16, 8), 256, 0, stream>>>(Sb, out_w, out_b, out);
}

// Round 2
// 2937.332 us; speedup vs baseline: 5.2982x; 5.2982x over previous
//
#include <hip/hip_runtime.h>
#include <hip/hip_bf16.h>

#define HH 128
#define WW 128

typedef _Float16 half8 __attribute__((ext_vector_type(8)));
typedef float f32x4 __attribute__((ext_vector_type(4)));

// ---------------------------------------------------------------------------
// Weight transform: fp32 [oc][ic][3][3] -> f16 [tap][oc][ic] per layer.
// Layers 0..15 rb_w1, 16..31 rb_w2, 32 body (OC=64), 33 super (OC padded 448).
// ---------------------------------------------------------------------------
__global__ __launch_bounds__(256)
void wxform_k(const float* __restrict__ rb_w1, const float* __restrict__ rb_w2,
              const float* __restrict__ body_w, const float* __restrict__ super_w,
              _Float16* __restrict__ Wt) {
    const int per64 = 64 * 64 * 9;          // 36864
    const int n64   = 33 * per64;           // 1216512
    const int total = n64 + 448 * 64 * 9;   // + 258048
    for (int i = blockIdx.x * 256 + threadIdx.x; i < total; i += gridDim.x * 256) {
        if (i < n64) {
            int l  = i / per64;
            int r  = i - l * per64;
            int ic = r & 63, oc = (r >> 6) & 63, tap = r >> 12;
            const float* src = (l < 16) ? (rb_w1 + (size_t)l * per64)
                             : (l < 32) ? (rb_w2 + (size_t)(l - 16) * per64)
                                        : body_w;
            Wt[i] = (_Float16)src[(oc * 64 + ic) * 9 + tap];
        } else {
            int r  = i - n64;
            int ic = r & 63;
            int oc = (r >> 6) % 448;
            int tap = (r >> 6) / 448;
            float v = (oc < 400) ? super_w[((size_t)oc * 64 + ic) * 9 + tap] : 0.f;
            Wt[i] = (_Float16)v;
        }
    }
}

// ---------------------------------------------------------------------------
// Head conv: 3 -> 64, fused mean subtraction. One thread per pixel.
// ---------------------------------------------------------------------------
__global__ __launch_bounds__(256)
void head_k(const float* __restrict__ x, const float* __restrict__ w,
            const float* __restrict__ b, float* __restrict__ out) {
    int n  = blockIdx.z;
    int gx = blockIdx.x * 16 + (threadIdx.x & 15);
    int gy = blockIdx.y * 16 + (threadIdx.x >> 4);
    float msub[3] = {255.0f * 0.4488f, 255.0f * 0.4371f, 255.0f * 0.4040f};
    float iv[27];
#pragma unroll
    for (int c = 0; c < 3; ++c)
#pragma unroll
        for (int dy = 0; dy < 3; ++dy)
#pragma unroll
            for (int dx = 0; dx < 3; ++dx) {
                int yy = gy + dy - 1, xx = gx + dx - 1;
                float v = 0.f;
                if ((unsigned)yy < HH && (unsigned)xx < WW)
                    v = x[(((size_t)n * 3 + c) * HH + yy) * WW + xx] - msub[c];
                iv[c * 9 + dy * 3 + dx] = v;
            }
    for (int oc = 0; oc < 64; ++oc) {
        float a = b[oc];
#pragma unroll
        for (int t = 0; t < 27; ++t) a = fmaf(iv[t], w[oc * 27 + t], a);
        out[(((size_t)n * 64 + oc) * HH + gy) * WW + gx] = a;
    }
}

// ---------------------------------------------------------------------------
// MFMA implicit-GEMM 3x3 conv, IC=64. Block: 64 oc x 16x16 px, 4 waves.
// Wave: 4 output rows x 16 x x 64 oc (4 oc-tiles of 16).
// LDS: full 64-ic 18x18 input tile, f16, xor-swizzled [px][ic].
// dy-folding: 6 data-row B-frags per (ic32,dx) feed 3 dy taps x 4 oc-tiles.
// A-frags read from pre-transformed f16 weights [tap][oc][ic] (L1/L2-hot).
// ---------------------------------------------------------------------------
template<bool RELU, bool RES, bool OUT_F16>
__global__ __launch_bounds__(256, 2)
void mconv_k(const float* __restrict__ in, const _Float16* __restrict__ Wt,
             const float* __restrict__ bias, const float* __restrict__ resid,
             void* __restrict__ outp, int OCp, int OCr) {
    __shared__ _Float16 sIn[18 * 18 * 64];  // 41472 f16 = 41.5 KB

    int tid = threadIdx.x;
    int octz = OCp >> 6;
    int n      = blockIdx.z / octz;
    int ocbase = (blockIdx.z % octz) << 6;
    int bx = blockIdx.x, by = blockIdx.y;

    // ---- stage input tile (fp32 global -> f16 LDS, zero halo) ----
    const size_t inBase = (size_t)n * 64 * (HH * WW);
    for (int i = tid; i < 18 * 18 * 64; i += 256) {
        int ic  = i / 324;
        int rem = i - ic * 324;
        int py  = rem / 18;
        int px  = rem - py * 18;
        int gy = by * 16 + py - 1, gx = bx * 16 + px - 1;
        float v = 0.f;
        if ((unsigned)gy < (unsigned)HH && (unsigned)gx < (unsigned)WW)
            v = in[inBase + (size_t)ic * (HH * WW) + gy * WW + gx];
        int pl = py * 18 + px;
        sIn[pl * 64 + (((ic >> 3) ^ (pl & 7)) << 3) + (ic & 7)] = (_Float16)v;
    }
    __syncthreads();

    int wv   = tid >> 6;
    int lane = tid & 63;
    int lx = lane & 15, lg = lane >> 4;

    f32x4 acc[4][4];  // [row][octile]
#pragma unroll
    for (int r = 0; r < 4; ++r)
#pragma unroll
        for (int t = 0; t < 4; ++t) acc[r][t] = (f32x4){0.f, 0.f, 0.f, 0.f};

#pragma unroll
    for (int icstep = 0; icstep < 2; ++icstep) {
        int icoff = icstep * 32 + lg * 8;
        int icg   = icoff >> 3;
#pragma unroll
        for (int dx = 0; dx < 3; ++dx) {
            half8 Bf[6];
#pragma unroll
            for (int d = 0; d < 6; ++d) {
                int pl = (wv * 4 + d) * 18 + lx + dx;
                Bf[d] = *(const half8*)&sIn[pl * 64 + ((icg ^ (pl & 7)) << 3)];
            }
#pragma unroll
            for (int dy = 0; dy < 3; ++dy) {
                int tap = dy * 3 + dx;
                half8 Af[4];
#pragma unroll
                for (int t = 0; t < 4; ++t) {
                    int oc = ocbase + t * 16 + lx;
                    Af[t] = *(const half8*)&Wt[((size_t)(tap * OCp + oc)) * 64 + icoff];
                }
#pragma unroll
                for (int r = 0; r < 4; ++r) {
#pragma unroll
                    for (int t = 0; t < 4; ++t)
                        acc[r][t] = __builtin_amdgcn_mfma_f32_16x16x32_f16(
                            Af[t], Bf[r + dy], acc[r][t], 0, 0, 0);
                }
            }
        }
    }

    // ---- epilogue ----
    int gx0 = bx * 16 + lx;
    int gy0 = by * 16 + wv * 4;
#pragma unroll
    for (int r = 0; r < 4; ++r) {
        int y = gy0 + r;
#pragma unroll
        for (int t = 0; t < 4; ++t) {
#pragma unroll
            for (int q = 0; q < 4; ++q) {
                int oc = ocbase + t * 16 + lg * 4 + q;
                if (oc >= OCr) continue;
                float v = acc[r][t][q] + bias[oc];
                if (RELU) v = fmaxf(v, 0.f);
                size_t oi = (((size_t)n * OCr + oc) * HH + y) * WW + gx0;
                if (RES) v += resid[oi];
                if (OUT_F16) ((_Float16*)outp)[oi] = (_Float16)v;
                else         ((float*)outp)[oi]    = v;
            }
        }
    }
}

// ---------------------------------------------------------------------------
// Out conv: 100 -> 3 at 256x256 over pixel-shuffled super output (f16).
// t[n,c,y,x] = S[n, c*4 + (y&1)*2 + (x&1), y>>1, x>>1]; fused mean add.
// ---------------------------------------------------------------------------
__global__ __launch_bounds__(256)
void out_k(const _Float16* __restrict__ S, const float* __restrict__ w,
           const float* __restrict__ b, float* __restrict__ out) {
    int n = blockIdx.z;
    int x = blockIdx.x * 16 + (threadIdx.x & 15);
    int y = blockIdx.y * 16 + (threadIdx.x >> 4);
    float acc0 = 0.f, acc1 = 0.f, acc2 = 0.f;
    for (int ic = 0; ic < 100; ++ic) {
#pragma unroll
        for (int dy = 0; dy < 3; ++dy) {
            int yy = y + dy - 1;
            if ((unsigned)yy >= 256u) continue;
#pragma unroll
            for (int dx = 0; dx < 3; ++dx) {
                int xx = x + dx - 1;
                if ((unsigned)xx >= 256u) continue;
                int ch = ic * 4 + (yy & 1) * 2 + (xx & 1);
                float v = (float)S[(((size_t)n * 400 + ch) * 128 + (yy >> 1)) * 128 + (xx >> 1)];
                int t = dy * 3 + dx;
                acc0 = fmaf(v, w[(0 * 100 + ic) * 9 + t], acc0);
                acc1 = fmaf(v, w[(1 * 100 + ic) * 9 + t], acc1);
                acc2 = fmaf(v, w[(2 * 100 + ic) * 9 + t], acc2);
            }
        }
    }
    const float m0 = 255.0f * 0.4488f, m1 = 255.0f * 0.4371f, m2 = 255.0f * 0.4040f;
    size_t base = ((size_t)n * 3) * 256 * 256 + (size_t)y * 256 + x;
    out[base]                 = acc0 + b[0] + m0;
    out[base + 256 * 256]     = acc1 + b[1] + m1;
    out[base + 2 * 256 * 256] = acc2 + b[2] + m2;
}

// ---------------------------------------------------------------------------
extern "C" void kernel_launch(void* const* d_in, const int* in_sizes, int n_in,
                              void* d_out, int out_size, void* d_ws, size_t ws_size,
                              hipStream_t stream) {
    const float* x       = (const float*)d_in[0];
    const float* head_w  = (const float*)d_in[1];
    const float* head_b  = (const float*)d_in[2];
    const float* rb_w1   = (const float*)d_in[3];
    const float* rb_b1   = (const float*)d_in[4];
    const float* rb_w2   = (const float*)d_in[5];
    const float* rb_b2   = (const float*)d_in[6];
    const float* body_w  = (const float*)d_in[7];
    const float* body_b  = (const float*)d_in[8];
    const float* super_w = (const float*)d_in[9];
    const float* super_b = (const float*)d_in[10];
    const float* out_w   = (const float*)d_in[11];
    const float* out_b   = (const float*)d_in[12];
    float* out = (float*)d_out;

    const size_t act = (size_t)8 * 64 * HH * WW;  // 8,388,608 floats
    float* Tb = (float*)d_ws;                     // [0, act) floats
    float* Hb = Tb + act;                         // [act, 2act)
    float* Cb = Hb + act;                         // [2act, 3act)
    // Sb (f16, 8*400*128*128) overlaps Hb+Cb (dead by super time), NOT Tb.
    _Float16* Sb = (_Float16*)Hb;
    // Wt after Sb's span: Sb bytes = 104857600, starting at byte act*4.
    _Float16* Wt = (_Float16*)((char*)d_ws + (size_t)act * 4 + 104857600);

    // 0) weight transform (f16 [tap][oc][ic])
    wxform_k<<<dim3(1440), 256, 0, stream>>>(rb_w1, rb_w2, body_w, super_w, Wt);

    // 1) head
    head_k<<<dim3(8, 8, 8), 256, 0, stream>>>(x, head_w, head_b, Hb);

    // 2) resblocks
    const _Float16* Wt_rb1 = Wt;
    const _Float16* Wt_rb2 = Wt + (size_t)16 * 36864;
    const _Float16* Wt_bod = Wt + (size_t)32 * 36864;
    const _Float16* Wt_sup = Wt + (size_t)33 * 36864;
    dim3 cgrid(8, 8, 8);
    for (int i = 0; i < 16; ++i) {
        const float* cin = (i == 0) ? Hb : Cb;
        mconv_k<true, false, false><<<cgrid, 256, 0, stream>>>(
            cin, Wt_rb1 + (size_t)i * 36864, rb_b1 + i * 64, nullptr, Tb, 64, 64);
        mconv_k<false, true, false><<<cgrid, 256, 0, stream>>>(
            Tb, Wt_rb2 + (size_t)i * 36864, rb_b2 + i * 64, cin, Cb, 64, 64);
    }
    // 3) body conv + skip from head
    mconv_k<false, true, false><<<cgrid, 256, 0, stream>>>(
        Cb, Wt_bod, body_b, Hb, Tb, 64, 64);
    // 4) super conv 64->400 (padded 448), f16 out
    mconv_k<false, false, true><<<dim3(8, 8, 8 * 7), 256, 0, stream>>>(
        Tb, Wt_sup, super_b, nullptr, (void*)Sb, 448, 400);
    // 5) out conv over pixel-shuffled view + mean add
    out_k<<<dim3(16, 16, 8), 256, 0, stream>>>(Sb, out_w, out_b, out);
}

// Round 3
// 1753.960 us; speedup vs baseline: 8.8729x; 1.6747x over previous
//
#include <hip/hip_runtime.h>
#include <hip/hip_bf16.h>

#define HH 128
#define WW 128

typedef _Float16 half4_t __attribute__((ext_vector_type(4)));
typedef _Float16 half8 __attribute__((ext_vector_type(8)));
typedef float f32x4 __attribute__((ext_vector_type(4)));

// ---------------------------------------------------------------------------
// Weight transform: fp32 [oc][ic][3][3] -> f16 [tap][oc][ic] per layer.
// Layers 0..15 rb_w1, 16..31 rb_w2, 32 body (OC=64), 33 super (OC padded 448).
// ---------------------------------------------------------------------------
__global__ __launch_bounds__(256)
void wxform_k(const float* __restrict__ rb_w1, const float* __restrict__ rb_w2,
              const float* __restrict__ body_w, const float* __restrict__ super_w,
              _Float16* __restrict__ Wt) {
    const int per64 = 64 * 64 * 9;          // 36864
    const int n64   = 33 * per64;           // 1216512
    const int total = n64 + 448 * 64 * 9;   // + 258048
    for (int i = blockIdx.x * 256 + threadIdx.x; i < total; i += gridDim.x * 256) {
        if (i < n64) {
            int l  = i / per64;
            int r  = i - l * per64;
            int ic = r & 63, oc = (r >> 6) & 63, tap = r >> 12;
            const float* src = (l < 16) ? (rb_w1 + (size_t)l * per64)
                             : (l < 32) ? (rb_w2 + (size_t)(l - 16) * per64)
                                        : body_w;
            Wt[i] = (_Float16)src[(oc * 64 + ic) * 9 + tap];
        } else {
            int r   = i - n64;
            int ic  = r & 63;
            int oc  = (r >> 6) % 448;
            int tap = (r >> 6) / 448;
            float v = (oc < 400) ? super_w[((size_t)oc * 64 + ic) * 9 + tap] : 0.f;
            Wt[i] = (_Float16)v;
        }
    }
}

// ---------------------------------------------------------------------------
// Head conv: 3 -> 64, fused mean subtraction. Output f16 4c layout.
// ---------------------------------------------------------------------------
__global__ __launch_bounds__(256)
void head_k(const float* __restrict__ x, const float* __restrict__ w,
            const float* __restrict__ b, _Float16* __restrict__ out) {
    int n  = blockIdx.z;
    int gx = blockIdx.x * 16 + (threadIdx.x & 15);
    int gy = blockIdx.y * 16 + (threadIdx.x >> 4);
    float msub[3] = {255.0f * 0.4488f, 255.0f * 0.4371f, 255.0f * 0.4040f};
    float iv[27];
#pragma unroll
    for (int c = 0; c < 3; ++c)
#pragma unroll
        for (int dy = 0; dy < 3; ++dy)
#pragma unroll
            for (int dx = 0; dx < 3; ++dx) {
                int yy = gy + dy - 1, xx = gx + dx - 1;
                float v = 0.f;
                if ((unsigned)yy < HH && (unsigned)xx < WW)
                    v = x[(((size_t)n * 3 + c) * HH + yy) * WW + xx] - msub[c];
                iv[c * 9 + dy * 3 + dx] = v;
            }
    for (int ocg = 0; ocg < 16; ++ocg) {
        half4_t o;
#pragma unroll
        for (int q = 0; q < 4; ++q) {
            int oc  = ocg * 4 + q;
            float a = b[oc];
#pragma unroll
            for (int t = 0; t < 27; ++t) a = fmaf(iv[t], w[oc * 27 + t], a);
            o[q] = (_Float16)a;
        }
        *(half4_t*)&out[((((size_t)n * 16 + ocg) * HH + gy) * WW + gx) * 4] = o;
    }
}

// ---------------------------------------------------------------------------
// MFMA implicit-GEMM 3x3 conv, IC=64, activations f16 4c [n][c/4][y][x][4].
// Block: 16x16 px, 4 waves; internal loop over 64-oc tiles (super = 7).
// LDS: 18x18x64 f16 tile, xor-swizzled [px][ic]; staging = 2x8B loads ->
// one 16B LDS write per (px, 8ic) granule. dy-folding: 6 row B-frags per
// (ic32,dx) feed 3 dy taps x 4 oc-tiles (48 MFMA / 6 LDS reads).
// Epilogue: 4 oc packed per lane -> 8B stores; residual = 8B granule loads.
// ---------------------------------------------------------------------------
template<bool RELU, bool RES>
__global__ __launch_bounds__(256, 2)
void mconv_k(const _Float16* __restrict__ in, const _Float16* __restrict__ Wt,
             const float* __restrict__ bias, const _Float16* __restrict__ resid,
             _Float16* __restrict__ out, int OCp, int OCr, int C4) {
    __shared__ __align__(16) _Float16 sIn[18 * 18 * 64];

    int tid = threadIdx.x;
    int n = blockIdx.z, bx = blockIdx.x, by = blockIdx.y;

    // ---- stage input tile: f16 4c global -> swizzled [px][ic] LDS ----
    for (int i = tid; i < 2592; i += 256) {
        int icg = i / 324;            // 8-ic group 0..7
        int pl  = i - icg * 324;      // pixel 0..323
        int py  = pl / 18, px = pl - py * 18;
        int gy = by * 16 + py - 1, gx = bx * 16 + px - 1;
        half8 v = {0, 0, 0, 0, 0, 0, 0, 0};
        if ((unsigned)gy < (unsigned)HH && (unsigned)gx < (unsigned)WW) {
            size_t base = ((((size_t)n * 16 + icg * 2) * HH + gy) * WW + gx) * 4;
            half4_t a = *(const half4_t*)&in[base];
            half4_t c = *(const half4_t*)&in[base + (size_t)HH * WW * 4];
            v[0] = a[0]; v[1] = a[1]; v[2] = a[2]; v[3] = a[3];
            v[4] = c[0]; v[5] = c[1]; v[6] = c[2]; v[7] = c[3];
        }
        *(half8*)&sIn[pl * 64 + ((icg ^ (pl & 7)) << 3)] = v;
    }
    __syncthreads();

    int wv = tid >> 6, lane = tid & 63;
    int lx = lane & 15, lg = lane >> 4;
    int gx0 = bx * 16 + lx, gy0 = by * 16 + wv * 4;

    for (int ocb = 0; ocb < OCp; ocb += 64) {
        f32x4 acc[4][4];
#pragma unroll
        for (int r = 0; r < 4; ++r)
#pragma unroll
            for (int t = 0; t < 4; ++t) acc[r][t] = (f32x4){0.f, 0.f, 0.f, 0.f};

#pragma unroll
        for (int icstep = 0; icstep < 2; ++icstep) {
            int icoff = icstep * 32 + lg * 8;
            int icg   = icoff >> 3;
#pragma unroll
            for (int dx = 0; dx < 3; ++dx) {
                half8 Bf[6];
#pragma unroll
                for (int d = 0; d < 6; ++d) {
                    int pl = (wv * 4 + d) * 18 + lx + dx;
                    Bf[d] = *(const half8*)&sIn[pl * 64 + ((icg ^ (pl & 7)) << 3)];
                }
#pragma unroll
                for (int dy = 0; dy < 3; ++dy) {
                    int tap = dy * 3 + dx;
                    half8 Af[4];
#pragma unroll
                    for (int t = 0; t < 4; ++t)
                        Af[t] = *(const half8*)&Wt[
                            ((size_t)(tap * OCp + ocb + t * 16 + lx)) * 64 + icoff];
#pragma unroll
                    for (int r = 0; r < 4; ++r)
#pragma unroll
                        for (int t = 0; t < 4; ++t)
                            acc[r][t] = __builtin_amdgcn_mfma_f32_16x16x32_f16(
                                Af[t], Bf[r + dy], acc[r][t], 0, 0, 0);
                }
            }
        }

        // ---- epilogue: 8B granule stores ----
#pragma unroll
        for (int r = 0; r < 4; ++r) {
            int y = gy0 + r;
#pragma unroll
            for (int t = 0; t < 4; ++t) {
                int oc0 = ocb + (t * 4 + lg) * 4;
                if (oc0 >= OCr) continue;
                f32x4 bv = *(const f32x4*)&bias[oc0];
                size_t gi = ((((size_t)n * C4 + (oc0 >> 2)) * HH + y) * WW + gx0) * 4;
                float vv[4];
#pragma unroll
                for (int q = 0; q < 4; ++q) {
                    float v = acc[r][t][q] + bv[q];
                    if (RELU) v = fmaxf(v, 0.f);
                    vv[q] = v;
                }
                if (RES) {
                    half4_t rg = *(const half4_t*)&resid[gi];
#pragma unroll
                    for (int q = 0; q < 4; ++q) vv[q] += (float)rg[q];
                }
                half4_t o;
#pragma unroll
                for (int q = 0; q < 4; ++q) o[q] = (_Float16)vv[q];
                *(half4_t*)&out[gi] = o;
            }
        }
    }
}

// ---------------------------------------------------------------------------
// Out conv 100->3 at 256x256 over pixel-shuffled super output. Super output
// is f16 4c [n][ic(100)][Y][X][sub] where sub = (y&1)*2 + (x&1) -- the 4c
// granule IS the 4 shuffle phases. Thread computes a 2x2 output quad from a
// 3x3 granule neighborhood; all tap indices compile-time. Fused mean add.
// ---------------------------------------------------------------------------
__global__ __launch_bounds__(256)
void out_k(const _Float16* __restrict__ S, const float* __restrict__ w,
           const float* __restrict__ b, float* __restrict__ out) {
    int n = blockIdx.z;
    int a  = blockIdx.y * 16 + (threadIdx.x >> 4);   // source row 0..127
    int bc = blockIdx.x * 16 + (threadIdx.x & 15);   // source col 0..127
    float acc[3][2][2];
#pragma unroll
    for (int c = 0; c < 3; ++c)
#pragma unroll
        for (int oy = 0; oy < 2; ++oy)
#pragma unroll
            for (int ox = 0; ox < 2; ++ox) acc[c][oy][ox] = 0.f;

    for (int ic = 0; ic < 100; ++ic) {
        float g[3][3][4];
#pragma unroll
        for (int yi = 0; yi < 3; ++yi) {
            int Y = a - 1 + yi;
#pragma unroll
            for (int xi = 0; xi < 3; ++xi) {
                int X = bc - 1 + xi;
                half4_t h = {0, 0, 0, 0};
                if ((unsigned)Y < 128u && (unsigned)X < 128u)
                    h = *(const half4_t*)&S[((((size_t)n * 100 + ic) * 128 + Y) * 128 + X) * 4];
#pragma unroll
                for (int s = 0; s < 4; ++s) g[yi][xi][s] = (float)h[s];
            }
        }
#pragma unroll
        for (int oy = 0; oy < 2; ++oy)
#pragma unroll
            for (int ox = 0; ox < 2; ++ox)
#pragma unroll
                for (int dy = 0; dy < 3; ++dy)
#pragma unroll
                    for (int dx = 0; dx < 3; ++dx) {
                        // yy = 2a + oy + dy - 1; e = oy+dy-1 in [-1,2]
                        const int ey = oy + dy - 1, ex = ox + dx - 1;
                        const int yi = (ey >> 1) + 1, xi = (ex >> 1) + 1;  // floor(e/2)+1
                        const int sub = (ey & 1) * 2 + (ex & 1);
                        float v = g[yi][xi][sub];
#pragma unroll
                        for (int c = 0; c < 3; ++c)
                            acc[c][oy][ox] = fmaf(v, w[(c * 100 + ic) * 9 + dy * 3 + dx],
                                                  acc[c][oy][ox]);
                    }
    }
    const float madd[3] = {255.0f * 0.4488f, 255.0f * 0.4371f, 255.0f * 0.4040f};
#pragma unroll
    for (int c = 0; c < 3; ++c)
#pragma unroll
        for (int oy = 0; oy < 2; ++oy)
#pragma unroll
            for (int ox = 0; ox < 2; ++ox)
                out[(((size_t)n * 3 + c) * 256 + 2 * a + oy) * 256 + 2 * bc + ox] =
                    acc[c][oy][ox] + b[c] + madd[c];
}

// ---------------------------------------------------------------------------
extern "C" void kernel_launch(void* const* d_in, const int* in_sizes, int n_in,
                              void* d_out, int out_size, void* d_ws, size_t ws_size,
                              hipStream_t stream) {
    const float* x       = (const float*)d_in[0];
    const float* head_w  = (const float*)d_in[1];
    const float* head_b  = (const float*)d_in[2];
    const float* rb_w1   = (const float*)d_in[3];
    const float* rb_b1   = (const float*)d_in[4];
    const float* rb_w2   = (const float*)d_in[5];
    const float* rb_b2   = (const float*)d_in[6];
    const float* body_w  = (const float*)d_in[7];
    const float* body_b  = (const float*)d_in[8];
    const float* super_w = (const float*)d_in[9];
    const float* super_b = (const float*)d_in[10];
    const float* out_w   = (const float*)d_in[11];
    const float* out_b   = (const float*)d_in[12];
    float* out = (float*)d_out;

    // f16 activation buffers (16.78 MB each); Sb aliases Hb..beyond (dead then)
    const size_t ACT = (size_t)16777216;  // bytes per activation buffer
    char* wsb = (char*)d_ws;
    _Float16* Tb = (_Float16*)wsb;
    _Float16* Hb = (_Float16*)(wsb + ACT);
    _Float16* Cb = (_Float16*)(wsb + 2 * ACT);
    _Float16* Sb = (_Float16*)(wsb + ACT);             // 104857600 B span
    _Float16* Wt = (_Float16*)(wsb + ACT + 104857600); // 2949120 B

    // 0) weight transform
    wxform_k<<<dim3(1440), 256, 0, stream>>>(rb_w1, rb_w2, body_w, super_w, Wt);

    // 1) head
    head_k<<<dim3(8, 8, 8), 256, 0, stream>>>(x, head_w, head_b, Hb);

    const _Float16* Wt_rb1 = Wt;
    const _Float16* Wt_rb2 = Wt + (size_t)16 * 36864;
    const _Float16* Wt_bod = Wt + (size_t)32 * 36864;
    const _Float16* Wt_sup = Wt + (size_t)33 * 36864;
    dim3 cgrid(8, 8, 8);
    // 2) resblocks
    for (int i = 0; i < 16; ++i) {
        const _Float16* cin = (i == 0) ? Hb : Cb;
        mconv_k<true, false><<<cgrid, 256, 0, stream>>>(
            cin, Wt_rb1 + (size_t)i * 36864, rb_b1 + i * 64, nullptr, Tb, 64, 64, 16);
        mconv_k<false, true><<<cgrid, 256, 0, stream>>>(
            Tb, Wt_rb2 + (size_t)i * 36864, rb_b2 + i * 64, cin, Cb, 64, 64, 16);
    }
    // 3) body conv + skip from head
    mconv_k<false, true><<<cgrid, 256, 0, stream>>>(
        Cb, Wt_bod, body_b, Hb, Tb, 64, 64, 16);
    // 4) super conv 64->400 (padded 448), oc-tiles looped in-block
    mconv_k<false, false><<<cgrid, 256, 0, stream>>>(
        Tb, Wt_sup, super_b, nullptr, Sb, 448, 400, 100);
    // 5) out conv over pixel-shuffled granules + mean add
    out_k<<<dim3(8, 8, 8), 256, 0, stream>>>(Sb, out_w, out_b, out);
}

// Round 5
// 1581.667 us; speedup vs baseline: 9.8394x; 1.1089x over previous
//
#include <hip/hip_runtime.h>
#include <hip/hip_bf16.h>

#define HH 128
#define WW 128

typedef _Float16 half4_t __attribute__((ext_vector_type(4)));
typedef _Float16 half8 __attribute__((ext_vector_type(8)));
typedef float f32x4 __attribute__((ext_vector_type(4)));

// ---------------------------------------------------------------------------
// Weight transform: fp32 [oc][ic][3][3] -> f16 [tap][oc][ic] per layer.
// Layers 0..15 rb_w1, 16..31 rb_w2, 32 body (OC=64), 33 super (OC padded 448).
// ---------------------------------------------------------------------------
__global__ __launch_bounds__(256)
void wxform_k(const float* __restrict__ rb_w1, const float* __restrict__ rb_w2,
              const float* __restrict__ body_w, const float* __restrict__ super_w,
              _Float16* __restrict__ Wt) {
    const int per64 = 64 * 64 * 9;          // 36864
    const int n64   = 33 * per64;           // 1216512
    const int total = n64 + 448 * 64 * 9;   // + 258048
    for (int i = blockIdx.x * 256 + threadIdx.x; i < total; i += gridDim.x * 256) {
        if (i < n64) {
            int l  = i / per64;
            int r  = i - l * per64;
            int ic = r & 63, oc = (r >> 6) & 63, tap = r >> 12;
            const float* src = (l < 16) ? (rb_w1 + (size_t)l * per64)
                             : (l < 32) ? (rb_w2 + (size_t)(l - 16) * per64)
                                        : body_w;
            Wt[i] = (_Float16)src[(oc * 64 + ic) * 9 + tap];
        } else {
            int r   = i - n64;
            int ic  = r & 63;
            int oc  = (r >> 6) % 448;
            int tap = (r >> 6) / 448;
            float v = (oc < 400) ? super_w[((size_t)oc * 64 + ic) * 9 + tap] : 0.f;
            Wt[i] = (_Float16)v;
        }
    }
}

// ---------------------------------------------------------------------------
// Head conv: 3 -> 64, fused mean subtraction. Output f16 4c layout.
// ---------------------------------------------------------------------------
__global__ __launch_bounds__(256)
void head_k(const float* __restrict__ x, const float* __restrict__ w,
            const float* __restrict__ b, _Float16* __restrict__ out) {
    int n  = blockIdx.z;
    int gx = blockIdx.x * 16 + (threadIdx.x & 15);
    int gy = blockIdx.y * 16 + (threadIdx.x >> 4);
    float msub[3] = {255.0f * 0.4488f, 255.0f * 0.4371f, 255.0f * 0.4040f};
    float iv[27];
#pragma unroll
    for (int c = 0; c < 3; ++c)
#pragma unroll
        for (int dy = 0; dy < 3; ++dy)
#pragma unroll
            for (int dx = 0; dx < 3; ++dx) {
                int yy = gy + dy - 1, xx = gx + dx - 1;
                float v = 0.f;
                if ((unsigned)yy < HH && (unsigned)xx < WW)
                    v = x[(((size_t)n * 3 + c) * HH + yy) * WW + xx] - msub[c];
                iv[c * 9 + dy * 3 + dx] = v;
            }
    for (int ocg = 0; ocg < 16; ++ocg) {
        half4_t o;
#pragma unroll
        for (int q = 0; q < 4; ++q) {
            int oc  = ocg * 4 + q;
            float a = b[oc];
#pragma unroll
            for (int t = 0; t < 27; ++t) a = fmaf(iv[t], w[oc * 27 + t], a);
            o[q] = (_Float16)a;
        }
        *(half4_t*)&out[((((size_t)n * 16 + ocg) * HH + gy) * WW + gx) * 4] = o;
    }
}

// ---------------------------------------------------------------------------
// Fused resblock: out = in + conv2(relu(conv1(in))). Tile: 16x8 conv2-out px.
// LDS: sIn 20x12x64 (halo +-2) + sMid 18x10x64 (conv1 out, halo +-1), both
// f16 xor-swizzled [px][ic]. conv1: 4 waves = 2 row-chunks x 2 overlapping
// px-16 tiles (overlap writes identical values -> benign). conv2: 4 waves =
// 2 row-groups x 2 oc-halves. Residual read from sIn (no global re-read).
// FIX (r4->r5): conv1 halo outputs OUTSIDE the image must be stored as ZERO
// in sMid (conv2's SAME padding pads conv1's *output* with zeros).
// ---------------------------------------------------------------------------
__global__ __launch_bounds__(256, 2)
void frb_k(const _Float16* __restrict__ in, const _Float16* __restrict__ W1,
           const _Float16* __restrict__ W2, const float* __restrict__ b1,
           const float* __restrict__ b2, _Float16* __restrict__ out) {
    __shared__ __align__(16) _Float16 sIn[12 * 20 * 64];   // 30.7 KB
    __shared__ __align__(16) _Float16 sMid[10 * 18 * 64];  // 23.0 KB

    int tid = threadIdx.x;
    int n = blockIdx.z, bx = blockIdx.x, by = blockIdx.y;

    // ---- stage input tile (f16 4c global -> swizzled [px][ic] LDS) ----
    for (int i = tid; i < 1920; i += 256) {
        int icg = i / 240, pl = i - icg * 240;
        int py = pl / 20, px = pl - py * 20;
        int gy = by * 8 + py - 2, gx = bx * 16 + px - 2;
        half8 v = {0, 0, 0, 0, 0, 0, 0, 0};
        if ((unsigned)gy < (unsigned)HH && (unsigned)gx < (unsigned)WW) {
            size_t base = ((((size_t)n * 16 + icg * 2) * HH + gy) * WW + gx) * 4;
            half4_t a = *(const half4_t*)&in[base];
            half4_t c = *(const half4_t*)&in[base + (size_t)HH * WW * 4];
            v[0] = a[0]; v[1] = a[1]; v[2] = a[2]; v[3] = a[3];
            v[4] = c[0]; v[5] = c[1]; v[6] = c[2]; v[7] = c[3];
        }
        *(half8*)&sIn[pl * 64 + ((icg ^ (pl & 7)) << 3)] = v;
    }
    __syncthreads();

    int wv = tid >> 6, lane = tid & 63;
    int lx = lane & 15, lg = lane >> 4;

    // ---- conv1: rows c0..c0+4 (c0 = -1 or 4), px p0+lx (p0 = -1 or 1) ----
    {
        int c0 = -1 + (wv >> 1) * 5;
        int p0 = -1 + (wv & 1) * 2;
        f32x4 acc[5][4];
#pragma unroll
        for (int r = 0; r < 5; ++r)
#pragma unroll
            for (int t = 0; t < 4; ++t) acc[r][t] = (f32x4){0.f, 0.f, 0.f, 0.f};

#pragma unroll
        for (int icstep = 0; icstep < 2; ++icstep) {
            int icoff = icstep * 32 + lg * 8;
            int icg   = icoff >> 3;
#pragma unroll
            for (int dx = 0; dx < 3; ++dx) {
                half8 Bf[7];
#pragma unroll
                for (int d = 0; d < 7; ++d) {
                    int pl = (c0 + d + 1) * 20 + (p0 + lx + dx + 1);
                    Bf[d] = *(const half8*)&sIn[pl * 64 + ((icg ^ (pl & 7)) << 3)];
                }
#pragma unroll
                for (int dy = 0; dy < 3; ++dy) {
                    int tap = dy * 3 + dx;
                    half8 Af[4];
#pragma unroll
                    for (int t = 0; t < 4; ++t)
                        Af[t] = *(const half8*)&W1[((size_t)(tap * 64 + t * 16 + lx)) * 64 + icoff];
#pragma unroll
                    for (int r = 0; r < 5; ++r)
#pragma unroll
                        for (int t = 0; t < 4; ++t)
                            acc[r][t] = __builtin_amdgcn_mfma_f32_16x16x32_f16(
                                Af[t], Bf[r + dy], acc[r][t], 0, 0, 0);
                }
            }
        }
        // epilogue -> sMid (bias + relu, f16); zero if outside image
        int gcol = bx * 16 + p0 + lx;                 // global conv1-out col
        bool colok = (unsigned)gcol < (unsigned)WW;
#pragma unroll
        for (int r = 0; r < 5; ++r) {
            int row  = c0 + r + 1;                    // sMid row 0..9
            int grow = by * 8 + c0 + r;               // global conv1-out row
            bool ok  = colok && ((unsigned)grow < (unsigned)HH);
#pragma unroll
            for (int t = 0; t < 4; ++t) {
                int oc0 = t * 16 + lg * 4;
                f32x4 bv = *(const f32x4*)&b1[oc0];
                int pl2 = row * 18 + (p0 + lx + 1);
                half4_t o;
#pragma unroll
                for (int q = 0; q < 4; ++q)
                    o[q] = ok ? (_Float16)fmaxf(acc[r][t][q] + bv[q], 0.f)
                              : (_Float16)0.f;
                *(half4_t*)&sMid[pl2 * 64 + (((oc0 >> 3) ^ (pl2 & 7)) << 3) + (oc0 & 4)] = o;
            }
        }
    }
    __syncthreads();

    // ---- conv2: rows r0..r0+3 (r0 = 0 or 4), oc-half h (32 oc) ----
    {
        int r0 = (wv & 1) * 4;
        int h  = wv >> 1;
        f32x4 acc[4][2];
#pragma unroll
        for (int r = 0; r < 4; ++r)
#pragma unroll
            for (int t = 0; t < 2; ++t) acc[r][t] = (f32x4){0.f, 0.f, 0.f, 0.f};

#pragma unroll
        for (int icstep = 0; icstep < 2; ++icstep) {
            int icoff = icstep * 32 + lg * 8;
            int icg   = icoff >> 3;
#pragma unroll
            for (int dx = 0; dx < 3; ++dx) {
                half8 Bf[6];
#pragma unroll
                for (int d = 0; d < 6; ++d) {
                    int pl = (r0 + d) * 18 + lx + dx;
                    Bf[d] = *(const half8*)&sMid[pl * 64 + ((icg ^ (pl & 7)) << 3)];
                }
#pragma unroll
                for (int dy = 0; dy < 3; ++dy) {
                    int tap = dy * 3 + dx;
                    half8 Af[2];
#pragma unroll
                    for (int t = 0; t < 2; ++t)
                        Af[t] = *(const half8*)&W2[((size_t)(tap * 64 + h * 32 + t * 16 + lx)) * 64 + icoff];
#pragma unroll
                    for (int r = 0; r < 4; ++r)
#pragma unroll
                        for (int t = 0; t < 2; ++t)
                            acc[r][t] = __builtin_amdgcn_mfma_f32_16x16x32_f16(
                                Af[t], Bf[r + dy], acc[r][t], 0, 0, 0);
                }
            }
        }
        // epilogue: + bias + residual(from sIn), store global f16 4c
        int gx0 = bx * 16 + lx;
#pragma unroll
        for (int r = 0; r < 4; ++r) {
            int y = by * 8 + r0 + r;
#pragma unroll
            for (int t = 0; t < 2; ++t) {
                int oc0 = h * 32 + t * 16 + lg * 4;
                f32x4 bv = *(const f32x4*)&b2[oc0];
                int pl = (r0 + r + 2) * 20 + lx + 2;
                half4_t rs = *(const half4_t*)&sIn[pl * 64 + (((oc0 >> 3) ^ (pl & 7)) << 3) + (oc0 & 4)];
                half4_t o;
#pragma unroll
                for (int q = 0; q < 4; ++q)
                    o[q] = (_Float16)(acc[r][t][q] + bv[q] + (float)rs[q]);
                *(half4_t*)&out[((((size_t)n * 16 + (oc0 >> 2)) * HH + y) * WW + gx0) * 4] = o;
            }
        }
    }
}

// ---------------------------------------------------------------------------
// MFMA conv, IC=64, 512 threads / 8 waves. Tile 16x16 px; waves = 4 row-groups
// x 2 oc-halves (32 oc each) looping oc in steps of 64. One shared LDS tile.
// ---------------------------------------------------------------------------
template<bool RES>
__global__ __launch_bounds__(512, 4)
void mconv_k(const _Float16* __restrict__ in, const _Float16* __restrict__ Wt,
             const float* __restrict__ bias, const _Float16* __restrict__ resid,
             _Float16* __restrict__ out, int OCp, int OCr, int C4) {
    __shared__ __align__(16) _Float16 sIn[18 * 18 * 64];  // 41.5 KB

    int tid = threadIdx.x;
    int n = blockIdx.z, bx = blockIdx.x, by = blockIdx.y;

    for (int i = tid; i < 2592; i += 512) {
        int icg = i / 324, pl = i - icg * 324;
        int py = pl / 18, px = pl - py * 18;
        int gy = by * 16 + py - 1, gx = bx * 16 + px - 1;
        half8 v = {0, 0, 0, 0, 0, 0, 0, 0};
        if ((unsigned)gy < (unsigned)HH && (unsigned)gx < (unsigned)WW) {
            size_t base = ((((size_t)n * 16 + icg * 2) * HH + gy) * WW + gx) * 4;
            half4_t a = *(const half4_t*)&in[base];
            half4_t c = *(const half4_t*)&in[base + (size_t)HH * WW * 4];
            v[0] = a[0]; v[1] = a[1]; v[2] = a[2]; v[3] = a[3];
            v[4] = c[0]; v[5] = c[1]; v[6] = c[2]; v[7] = c[3];
        }
        *(half8*)&sIn[pl * 64 + ((icg ^ (pl & 7)) << 3)] = v;
    }
    __syncthreads();

    int wv = tid >> 6, lane = tid & 63;
    int lx = lane & 15, lg = lane >> 4;
    int r0 = (wv & 3) * 4;
    int h  = wv >> 2;
    int gx0 = bx * 16 + lx;

    for (int ocb = h * 32; ocb < OCp; ocb += 64) {
        f32x4 acc[4][2];
#pragma unroll
        for (int r = 0; r < 4; ++r)
#pragma unroll
            for (int t = 0; t < 2; ++t) acc[r][t] = (f32x4){0.f, 0.f, 0.f, 0.f};

#pragma unroll
        for (int icstep = 0; icstep < 2; ++icstep) {
            int icoff = icstep * 32 + lg * 8;
            int icg   = icoff >> 3;
#pragma unroll
            for (int dx = 0; dx < 3; ++dx) {
                half8 Bf[6];
#pragma unroll
                for (int d = 0; d < 6; ++d) {
                    int pl = (r0 + d) * 18 + lx + dx;
                    Bf[d] = *(const half8*)&sIn[pl * 64 + ((icg ^ (pl & 7)) << 3)];
                }
#pragma unroll
                for (int dy = 0; dy < 3; ++dy) {
                    int tap = dy * 3 + dx;
                    half8 Af[2];
#pragma unroll
                    for (int t = 0; t < 2; ++t)
                        Af[t] = *(const half8*)&Wt[((size_t)(tap * OCp + ocb + t * 16 + lx)) * 64 + icoff];
#pragma unroll
                    for (int r = 0; r < 4; ++r)
#pragma unroll
                        for (int t = 0; t < 2; ++t)
                            acc[r][t] = __builtin_amdgcn_mfma_f32_16x16x32_f16(
                                Af[t], Bf[r + dy], acc[r][t], 0, 0, 0);
                }
            }
        }
#pragma unroll
        for (int r = 0; r < 4; ++r) {
            int y = by * 16 + r0 + r;
#pragma unroll
            for (int t = 0; t < 2; ++t) {
                int oc0 = ocb + t * 16 + lg * 4;
                if (oc0 >= OCr) continue;
                f32x4 bv = *(const f32x4*)&bias[oc0];
                size_t gi = ((((size_t)n * C4 + (oc0 >> 2)) * HH + y) * WW + gx0) * 4;
                float vv[4];
#pragma unroll
                for (int q = 0; q < 4; ++q) vv[q] = acc[r][t][q] + bv[q];
                if (RES) {
                    half4_t rg = *(const half4_t*)&resid[gi];
#pragma unroll
                    for (int q = 0; q < 4; ++q) vv[q] += (float)rg[q];
                }
                half4_t o;
#pragma unroll
                for (int q = 0; q < 4; ++q) o[q] = (_Float16)vv[q];
                *(half4_t*)&out[gi] = o;
            }
        }
    }
}

// ---------------------------------------------------------------------------
// Out conv 100->3 at 256x256 over pixel-shuffled super output (f16 4c; the
// 4c granule IS the 4 shuffle phases). Thread = 2x2 output quad. Mean add.
// ---------------------------------------------------------------------------
__global__ __launch_bounds__(256)
void out_k(const _Float16* __restrict__ S, const float* __restrict__ w,
           const float* __restrict__ b, float* __restrict__ out) {
    int n = blockIdx.z;
    int a  = blockIdx.y * 16 + (threadIdx.x >> 4);
    int bc = blockIdx.x * 16 + (threadIdx.x & 15);
    float acc[3][2][2];
#pragma unroll
    for (int c = 0; c < 3; ++c)
#pragma unroll
        for (int oy = 0; oy < 2; ++oy)
#pragma unroll
            for (int ox = 0; ox < 2; ++ox) acc[c][oy][ox] = 0.f;

    for (int ic = 0; ic < 100; ++ic) {
        float g[3][3][4];
#pragma unroll
        for (int yi = 0; yi < 3; ++yi) {
            int Y = a - 1 + yi;
#pragma unroll
            for (int xi = 0; xi < 3; ++xi) {
                int X = bc - 1 + xi;
                half4_t hv = {0, 0, 0, 0};
                if ((unsigned)Y < 128u && (unsigned)X < 128u)
                    hv = *(const half4_t*)&S[((((size_t)n * 100 + ic) * 128 + Y) * 128 + X) * 4];
#pragma unroll
                for (int s = 0; s < 4; ++s) g[yi][xi][s] = (float)hv[s];
            }
        }
#pragma unroll
        for (int oy = 0; oy < 2; ++oy)
#pragma unroll
            for (int ox = 0; ox < 2; ++ox)
#pragma unroll
                for (int dy = 0; dy < 3; ++dy)
#pragma unroll
                    for (int dx = 0; dx < 3; ++dx) {
                        const int ey = oy + dy - 1, ex = ox + dx - 1;
                        const int yi = (ey >> 1) + 1, xi = (ex >> 1) + 1;
                        const int sub = (ey & 1) * 2 + (ex & 1);
                        float v = g[yi][xi][sub];
#pragma unroll
                        for (int c = 0; c < 3; ++c)
                            acc[c][oy][ox] = fmaf(v, w[(c * 100 + ic) * 9 + dy * 3 + dx],
                                                  acc[c][oy][ox]);
                    }
    }
    const float madd[3] = {255.0f * 0.4488f, 255.0f * 0.4371f, 255.0f * 0.4040f};
#pragma unroll
    for (int c = 0; c < 3; ++c)
#pragma unroll
        for (int oy = 0; oy < 2; ++oy)
#pragma unroll
            for (int ox = 0; ox < 2; ++ox)
                out[(((size_t)n * 3 + c) * 256 + 2 * a + oy) * 256 + 2 * bc + ox] =
                    acc[c][oy][ox] + b[c] + madd[c];
}

// ---------------------------------------------------------------------------
extern "C" void kernel_launch(void* const* d_in, const int* in_sizes, int n_in,
                              void* d_out, int out_size, void* d_ws, size_t ws_size,
                              hipStream_t stream) {
    const float* x       = (const float*)d_in[0];
    const float* head_w  = (const float*)d_in[1];
    const float* head_b  = (const float*)d_in[2];
    const float* rb_w1   = (const float*)d_in[3];
    const float* rb_b1   = (const float*)d_in[4];
    const float* rb_w2   = (const float*)d_in[5];
    const float* rb_b2   = (const float*)d_in[6];
    const float* body_w  = (const float*)d_in[7];
    const float* body_b  = (const float*)d_in[8];
    const float* super_w = (const float*)d_in[9];
    const float* super_b = (const float*)d_in[10];
    const float* out_w   = (const float*)d_in[11];
    const float* out_b   = (const float*)d_in[12];
    float* out = (float*)d_out;

    const size_t ACT = (size_t)16777216;  // bytes per f16 activation buffer
    char* wsb = (char*)d_ws;
    _Float16* Tb = (_Float16*)wsb;                      // ping / body-out / super-in
    _Float16* Hb = (_Float16*)(wsb + ACT);              // head out (kept for body skip)
    _Float16* Cb = (_Float16*)(wsb + 2 * ACT);          // pong
    _Float16* Sb = (_Float16*)(wsb + ACT);              // super out (Hb/Cb dead then)
    _Float16* Wt = (_Float16*)(wsb + ACT + 104857600);

    // 0) weight transform
    wxform_k<<<dim3(1440), 256, 0, stream>>>(rb_w1, rb_w2, body_w, super_w, Wt);

    // 1) head
    head_k<<<dim3(8, 8, 8), 256, 0, stream>>>(x, head_w, head_b, Hb);

    const _Float16* Wt_bod = Wt + (size_t)32 * 36864;
    const _Float16* Wt_sup = Wt + (size_t)33 * 36864;

    // 2) fused resblocks (ping-pong Tb/Cb; Hb preserved)
    const _Float16* cur = Hb;
    for (int i = 0; i < 16; ++i) {
        _Float16* dst = (i & 1) ? Cb : Tb;
        frb_k<<<dim3(8, 16, 8), 256, 0, stream>>>(
            cur, Wt + (size_t)i * 36864, Wt + (size_t)(16 + i) * 36864,
            rb_b1 + i * 64, rb_b2 + i * 64, dst);
        cur = dst;
    }
    // cur == Cb after rb15
    // 3) body conv + head skip -> Tb
    mconv_k<true><<<dim3(8, 8, 8), 512, 0, stream>>>(
        Cb, Wt_bod, body_b, Hb, Tb, 64, 64, 16);
    // 4) super conv 64->400 (padded 448) -> Sb
    mconv_k<false><<<dim3(8, 8, 8), 512, 0, stream>>>(
        Tb, Wt_sup, super_b, nullptr, Sb, 448, 400, 100);
    // 5) out conv over pixel-shuffled granules + mean add
    out_k<<<dim3(8, 8, 8), 256, 0, stream>>>(Sb, out_w, out_b, out);
}